// Round 11
// baseline (123.781 us; speedup 1.0000x reference)
//
#include <hip/hip_runtime.h>
#include <hip/hip_bf16.h>

typedef _Float16 f16x8  __attribute__((ext_vector_type(8)));
typedef _Float16 f16x16 __attribute__((ext_vector_type(16)));
typedef float    f32x16 __attribute__((ext_vector_type(16)));
typedef float    v2f    __attribute__((ext_vector_type(2)));
typedef unsigned u32x4  __attribute__((ext_vector_type(4)));

#define LOG2E 1.442695040888963f

__device__ __forceinline__ unsigned pk16(float a, float b) {
    return __builtin_bit_cast(unsigned, __builtin_amdgcn_cvt_pkrtz(a, b));
}

// 32 rows per WAVE (was 64): per step only 2 MFMAs (gb=0,1) -> 32 live AGPRs
// + ~60 VGPR = ~95 total regs -> 5 waves/SIMD (r10 was stuck at 3: 72+64=136).
// Block = 4 waves = 128 rows; fc stage uses threads 0-127.
// Gate rows prescaled by exp2-arg factor (i,f,o: -log2e; g: +2log2e);
// c kept scaled (c' = 2log2e*c). 0.5 rcp per c-update, 0.5 per h-update.
__global__ __launch_bounds__(256, 4) void lstm_mfma_kernel(
    const float* __restrict__ mobility,  // [B,7]
    const float* __restrict__ controls,  // [B,5]
    const float* __restrict__ W_cc, const float* __restrict__ b_cc,
    const float* __restrict__ W_ih, const float* __restrict__ W_hh,
    const float* __restrict__ b_ih, const float* __restrict__ b_hh,
    const float* __restrict__ W1,  const float* __restrict__ b1,
    const float* __restrict__ W2,  const float* __restrict__ b2,
    const float* __restrict__ W3,  const float* __restrict__ b3,
    float* __restrict__ out, int Btot)
{
    __shared__ float hbuf[128][17];   // 8.7 KB, stride-17 conflict-free
    __shared__ float mobs[128][7];    // 3.5 KB

    const int tid  = threadIdx.x;
    const int lane = tid & 63;
    const int wib  = tid >> 6;        // 4 waves
    const int col  = lane & 31;       // row within the wave's 32-row tile
    const int hi   = lane >> 5;       // gu-half select

    const int blockRow0 = blockIdx.x * 128;

    // ---- stage this wave's 32 rows of mobility into LDS (wave-local) ----
    {
        float* dst = &mobs[wib * 32][0];                       // 224 floats
        const float* src = mobility + (size_t)(blockRow0 + wib * 32) * 7;
        #pragma unroll
        for (int j = 0; j < 4; ++j) {
            const int i = lane + j * 64;
            if (i < 224) dst[i] = src[i];
        }
    }

    // ---- A fragments: W_hh * rowscale -> f16 (8 regs, wave-shared weights) ----
    f16x8 afrag[2];
    #pragma unroll
    for (int gb = 0; gb < 2; ++gb) {
        const float s = (gb == 0) ? -LOG2E : ((col < 16) ? 2.0f * LOG2E : -LOG2E);
        const float* wr = W_hh + (gb * 32 + col) * 16 + hi * 8;
        u32x4 aw = { pk16(s * wr[0], s * wr[1]), pk16(s * wr[2], s * wr[3]),
                     pk16(s * wr[4], s * wr[5]), pk16(s * wr[6], s * wr[7]) };
        afrag[gb] = __builtin_bit_cast(f16x8, aw);
    }

    // ---- bias & W_ih in D-layout, prescaled, PACKED f16 (16 regs total) ----
    f16x16 bias_h[2], wih_h[2];
    #pragma unroll
    for (int gb = 0; gb < 2; ++gb)
        #pragma unroll
        for (int q = 0; q < 4; ++q) {
            const int gu = gb * 32 + 8 * q + 4 * hi;
            const float s = (gu < 32) ? -LOG2E : ((gu < 48) ? 2.0f * LOG2E : -LOG2E);
            #pragma unroll
            for (int e = 0; e < 4; ++e) {
                bias_h[gb][4 * q + e] = (_Float16)(s * (b_ih[gu + e] + b_hh[gu + e]));
                wih_h [gb][4 * q + e] = (_Float16)(s * W_ih[gu + e]);
            }
        }

    float c[8];
    #pragma unroll
    for (int u = 0; u < 8; ++u) c[u] = 0.0f;

    u32x4 bz = { 0u, 0u, 0u, 0u };
    f16x8 bfrag = __builtin_bit_cast(f16x8, bz);

    #pragma unroll 1   // rolled: keeps live ranges small
    for (int t = 0; t < 7; ++t) {
        const float xt = mobs[wib * 32 + col][t];   // ds_read_b32

        f32x16 cin0, cin1;
        #pragma unroll
        for (int r = 0; r < 16; ++r)
            cin0[r] = fmaf(xt, (float)wih_h[0][r], (float)bias_h[0][r]);   // fma_mix
        f32x16 a0 = __builtin_amdgcn_mfma_f32_32x32x16_f16(afrag[0], bfrag, cin0, 0, 0, 0);
        #pragma unroll
        for (int r = 0; r < 16; ++r)
            cin1[r] = fmaf(xt, (float)wih_h[1][r], (float)bias_h[1][r]);
        f32x16 a1 = __builtin_amdgcn_mfma_f32_32x32x16_f16(afrag[1], bfrag, cin1, 0, 0, 0);

        // pair-local update: all transients die inside each u-pair
        float h[8];
        #pragma unroll
        for (int u = 0; u < 8; u += 2) {
            const float ea0 = __builtin_amdgcn_exp2f(a0[u]);
            const float ef0 = __builtin_amdgcn_exp2f(a0[u + 8]);
            const float eb0 = __builtin_amdgcn_exp2f(a1[u]);
            const float eo0 = __builtin_amdgcn_exp2f(a1[u + 8]);
            const float ea1 = __builtin_amdgcn_exp2f(a0[u + 1]);
            const float ef1 = __builtin_amdgcn_exp2f(a0[u + 9]);
            const float eb1 = __builtin_amdgcn_exp2f(a1[u + 1]);
            const float eo1 = __builtin_amdgcn_exp2f(a1[u + 9]);

            const float pf0 = 1.0f + ef0, pa0 = 1.0f + ea0;
            const float pf1 = 1.0f + ef1, pa1 = 1.0f + ea1;
            const float den0 = fmaf(pa0, eb0, pa0);           // (1+ea)(eb+1)
            const float den1 = fmaf(pa1, eb1, pa1);
            const float D0 = den0 * pf0, D1 = den1 * pf1;
            const float num0 = fmaf(eb0, 2.0f * LOG2E, -2.0f * LOG2E);
            const float num1 = fmaf(eb1, 2.0f * LOG2E, -2.0f * LOG2E);
            const float cn0 = fmaf(c[u],     den0, num0 * pf0);
            const float cn1 = fmaf(c[u + 1], den1, num1 * pf1);
            const float rC = __builtin_amdgcn_rcpf(D0 * D1);
            const float cs0 = (cn0 * D1) * rC;
            const float cs1 = (cn1 * D0) * rC;
            c[u]     = cs0;
            c[u + 1] = cs1;
            const float ec0 = __builtin_amdgcn_exp2f(cs0);    // e^{2c}
            const float ec1 = __builtin_amdgcn_exp2f(cs1);
            const float ph0 = 1.0f + eo0, ph1 = 1.0f + eo1;
            const float dh0 = fmaf(ph0, ec0, ph0);            // (1+eo)(ec+1)
            const float dh1 = fmaf(ph1, ec1, ph1);
            const float rP = __builtin_amdgcn_rcpf(dh0 * dh1);
            h[u]     = ((ec0 - 1.0f) * dh1) * rP;
            h[u + 1] = ((ec1 - 1.0f) * dh0) * rP;
        }
        unsigned q0 = pk16(h[0], h[1]);
        unsigned q1 = pk16(h[2], h[3]);
        unsigned q2 = pk16(h[4], h[5]);
        unsigned q3 = pk16(h[6], h[7]);
        auto s02 = __builtin_amdgcn_permlane32_swap(q0, q2, false, false);
        auto s13 = __builtin_amdgcn_permlane32_swap(q1, q3, false, false);
        u32x4 bw = { s02[0], s13[0], s02[1], s13[1] };
        bfrag = __builtin_bit_cast(f16x8, bw);
    }

    // ---- final h straight from bfrag (B layout: lane holds units hi*8+e of col) ----
    {
        const int rr = wib * 32 + col;
        #pragma unroll
        for (int e = 0; e < 8; ++e)
            hbuf[rr][hi * 8 + e] = (float)bfrag[e];
    }
    __syncthreads();

    // ---- fc stage: threads 0-127 own one row each ----
    if (tid < 128) {
        const int grow = blockRow0 + tid;

        float x19[19];
        #pragma unroll
        for (int k = 0; k < 16; ++k) x19[k] = hbuf[tid][k];

        float ctl[5];
        #pragma unroll
        for (int k = 0; k < 5; ++k) ctl[k] = controls[grow * 5 + k];
        #pragma unroll
        for (int j = 0; j < 3; ++j) {
            float a = b_cc[j];
            #pragma unroll
            for (int k = 0; k < 5; ++k) a = fmaf(ctl[k], W_cc[j * 5 + k], a);
            x19[16 + j] = a;
        }

        // fc1: Linear(19->16); tanh via pairwise-merged rcp
        float d1[16];
        #pragma unroll
        for (int j = 0; j < 16; ++j) {
            float a = b1[j];
            #pragma unroll
            for (int k = 0; k < 19; ++k) a = fmaf(x19[k], W1[j * 19 + k], a);
            d1[j] = __builtin_amdgcn_exp2f((2.0f * LOG2E) * a) + 1.0f;
        }
        v2f t12[8];
        #pragma unroll
        for (int j = 0; j < 16; j += 2) {
            const float rP = __builtin_amdgcn_rcpf(d1[j] * d1[j + 1]);
            t12[j >> 1][0] = fmaf(-2.0f * d1[j + 1], rP, 1.0f);
            t12[j >> 1][1] = fmaf(-2.0f * d1[j],     rP, 1.0f);
        }

        // fc2: Linear(16->16) + tanh (packed fma, pairwise-merged rcp)
        float d2[16];
        #pragma unroll
        for (int j = 0; j < 16; ++j) {
            const v2f* w2row = (const v2f*)(W2 + j * 16);
            v2f a = t12[0] * w2row[0];
            #pragma unroll
            for (int p = 1; p < 8; ++p) a = __builtin_elementwise_fma(t12[p], w2row[p], a);
            d2[j] = __builtin_amdgcn_exp2f((2.0f * LOG2E) * (a.x + a.y + b2[j])) + 1.0f;
        }
        v2f t22[8];
        #pragma unroll
        for (int j = 0; j < 16; j += 2) {
            const float rP = __builtin_amdgcn_rcpf(d2[j] * d2[j + 1]);
            t22[j >> 1][0] = fmaf(-2.0f * d2[j + 1], rP, 1.0f);
            t22[j >> 1][1] = fmaf(-2.0f * d2[j],     rP, 1.0f);
        }

        // fc3: Linear(16->1) + ReLU
        const v2f* w3p = (const v2f*)W3;
        v2f a3 = t22[0] * w3p[0];
        #pragma unroll
        for (int p = 1; p < 8; ++p) a3 = __builtin_elementwise_fma(t22[p], w3p[p], a3);
        const float r = a3.x + a3.y + b3[0];
        if (grow < Btot) out[grow] = fmaxf(r, 0.0f);
    }
}

extern "C" void kernel_launch(void* const* d_in, const int* in_sizes, int n_in,
                              void* d_out, int out_size, void* d_ws, size_t ws_size,
                              hipStream_t stream) {
    const float* mobility = (const float*)d_in[0];
    const float* controls = (const float*)d_in[1];
    // d_in[2] = last : unused by the reference
    const float* W_cc = (const float*)d_in[3];
    const float* b_cc = (const float*)d_in[4];
    const float* W_ih = (const float*)d_in[5];
    const float* W_hh = (const float*)d_in[6];
    const float* b_ih = (const float*)d_in[7];
    const float* b_hh = (const float*)d_in[8];
    const float* W1   = (const float*)d_in[9];
    const float* b1   = (const float*)d_in[10];
    const float* W2   = (const float*)d_in[11];
    const float* b2   = (const float*)d_in[12];
    const float* W3   = (const float*)d_in[13];
    const float* b3   = (const float*)d_in[14];
    float* out = (float*)d_out;

    const int Btot = in_sizes[0] / 7;          // 1048576
    const int grid = (Btot + 127) / 128;       // 128 rows per block (4 waves x 32)

    lstm_mfma_kernel<<<grid, 256, 0, stream>>>(
        mobility, controls, W_cc, b_cc, W_ih, W_hh, b_ih, b_hh,
        W1, b1, W2, b2, W3, b3, out, Btot);
}

// Round 12
// 113.879 us; speedup vs baseline: 1.0870x; 1.0870x over previous
//
#include <hip/hip_runtime.h>
#include <hip/hip_bf16.h>

typedef _Float16 f16x8  __attribute__((ext_vector_type(8)));
typedef _Float16 f16x16 __attribute__((ext_vector_type(16)));
typedef float    f32x16 __attribute__((ext_vector_type(16)));
typedef float    v2f    __attribute__((ext_vector_type(2)));
typedef unsigned u32x4  __attribute__((ext_vector_type(4)));

#define LOG2E 1.442695040888963f

__device__ __forceinline__ unsigned pk16(float a, float b) {
    return __builtin_bit_cast(unsigned, __builtin_amdgcn_cvt_pkrtz(a, b));
}
__device__ __forceinline__ float fexp2(float x) { return __builtin_amdgcn_exp2f(x); }

// r8 structure (64 rows/wave, 4 waves/block, rolled t-loop, (256,3)) plus:
//  - unit-pair LSTM update in v2f so the compiler emits packed fp32
//    (v_pk_fma_f32/v_pk_mul_f32, full-rate on CDNA) -> ~7% fewer issue cycles
//  - grid-stride over 4 tiles per block (grid=1024): W_hh/bias/W_ih fragment
//    setup amortized 4x (~4%)
// Occupancy pushes are a dead axis: VALUBusy pinned ~80% across 22/31/38%
// occupancy (r6/r8/r11) -> issue-port saturated; only issue-count reduction pays.
__global__ __launch_bounds__(256, 3) void lstm_mfma_kernel(
    const float* __restrict__ mobility,  // [B,7]
    const float* __restrict__ controls,  // [B,5]
    const float* __restrict__ W_cc, const float* __restrict__ b_cc,
    const float* __restrict__ W_ih, const float* __restrict__ W_hh,
    const float* __restrict__ b_ih, const float* __restrict__ b_hh,
    const float* __restrict__ W1,  const float* __restrict__ b1,
    const float* __restrict__ W2,  const float* __restrict__ b2,
    const float* __restrict__ W3,  const float* __restrict__ b3,
    float* __restrict__ out, int Btot)
{
    __shared__ float hbuf[256][17];   // stride-17: conflict-free

    const int tid  = threadIdx.x;
    const int lane = tid & 63;
    const int wib  = tid >> 6;
    const int col  = lane & 31;
    const int hi   = lane >> 5;

    // ---- weights once per block; reused across grid-stride tiles ----
    f16x8 afrag[2];
    #pragma unroll
    for (int gb = 0; gb < 2; ++gb) {
        const float s = (gb == 0) ? -LOG2E : ((col < 16) ? 2.0f * LOG2E : -LOG2E);
        const float* wr = W_hh + (gb * 32 + col) * 16 + hi * 8;
        u32x4 aw = { pk16(s * wr[0], s * wr[1]), pk16(s * wr[2], s * wr[3]),
                     pk16(s * wr[4], s * wr[5]), pk16(s * wr[6], s * wr[7]) };
        afrag[gb] = __builtin_bit_cast(f16x8, aw);
    }
    f16x16 bias_h[2], wih_h[2];
    #pragma unroll
    for (int gb = 0; gb < 2; ++gb)
        #pragma unroll
        for (int q = 0; q < 4; ++q) {
            const int gu = gb * 32 + 8 * q + 4 * hi;
            const float s = (gu < 32) ? -LOG2E : ((gu < 48) ? 2.0f * LOG2E : -LOG2E);
            #pragma unroll
            for (int e = 0; e < 4; ++e) {
                bias_h[gb][4 * q + e] = (_Float16)(s * (b_ih[gu + e] + b_hh[gu + e]));
                wih_h [gb][4 * q + e] = (_Float16)(s * W_ih[gu + e]);
            }
        }

    const v2f one   = { 1.0f, 1.0f };
    const v2f twoL  = { 2.0f * LOG2E, 2.0f * LOG2E };
    const v2f ntwoL = { -2.0f * LOG2E, -2.0f * LOG2E };

    const int tilesTotal = (Btot + 255) >> 8;      // 4096
    for (int tile = blockIdx.x; tile < tilesTotal; tile += gridDim.x) {
        const int blockRow0 = tile * 256;
        const int r_lo = blockRow0 + wib * 64 + col;
        const int r_hi = r_lo + 32;

        float mlo[7], mhi[7];
        #pragma unroll
        for (int t = 0; t < 7; ++t) { mlo[t] = mobility[(size_t)r_lo * 7 + t]; mhi[t] = mobility[(size_t)r_hi * 7 + t]; }

        float c[2][8];
        #pragma unroll
        for (int rb = 0; rb < 2; ++rb)
            #pragma unroll
            for (int u = 0; u < 8; ++u) c[rb][u] = 0.0f;

        u32x4 bz = { 0u, 0u, 0u, 0u };
        f16x8 bfrag[2];
        bfrag[0] = __builtin_bit_cast(f16x8, bz);
        bfrag[1] = __builtin_bit_cast(f16x8, bz);

        #pragma unroll 1   // rolled: keeps live ranges small (r7 lesson)
        for (int t = 0; t < 7; ++t) {
            #pragma unroll
            for (int rb = 0; rb < 2; ++rb) {
                const float xt = rb ? mhi[t] : mlo[t];

                f32x16 cin0, cin1;
                #pragma unroll
                for (int r = 0; r < 16; ++r)
                    cin0[r] = fmaf(xt, (float)wih_h[0][r], (float)bias_h[0][r]);  // fma_mix
                f32x16 a0 = __builtin_amdgcn_mfma_f32_32x32x16_f16(afrag[0], bfrag[rb], cin0, 0, 0, 0);
                #pragma unroll
                for (int r = 0; r < 16; ++r)
                    cin1[r] = fmaf(xt, (float)wih_h[1][r], (float)bias_h[1][r]);
                f32x16 a1 = __builtin_amdgcn_mfma_f32_32x32x16_f16(afrag[1], bfrag[rb], cin1, 0, 0, 0);

                // unit-pair update, v2f -> packed fp32; trans stay scalar
                float h[8];
                #pragma unroll
                for (int u = 0; u < 8; u += 2) {
                    v2f ea = { fexp2(a0[u]),     fexp2(a0[u + 1]) };   // e^{-gi}
                    v2f ef = { fexp2(a0[u + 8]), fexp2(a0[u + 9]) };   // e^{-gf}
                    v2f eb = { fexp2(a1[u]),     fexp2(a1[u + 1]) };   // e^{2gg}
                    v2f eo = { fexp2(a1[u + 8]), fexp2(a1[u + 9]) };   // e^{-go}
                    v2f pf  = one + ef;
                    v2f pa  = one + ea;
                    v2f den = __builtin_elementwise_fma(pa, eb, pa);   // (1+ea)(eb+1)
                    v2f D   = den * pf;
                    v2f num = __builtin_elementwise_fma(eb, twoL, ntwoL);
                    v2f cv  = { c[rb][u], c[rb][u + 1] };
                    v2f cn  = __builtin_elementwise_fma(cv, den, num * pf);
                    const float rC = __builtin_amdgcn_rcpf(D[0] * D[1]);
                    v2f Dsw = { D[1], D[0] };
                    v2f rCv = { rC, rC };
                    v2f cs  = (cn * Dsw) * rCv;
                    c[rb][u]     = cs[0];
                    c[rb][u + 1] = cs[1];
                    v2f ec = { fexp2(cs[0]), fexp2(cs[1]) };           // e^{2c}
                    v2f ph = one + eo;
                    v2f dh = __builtin_elementwise_fma(ph, ec, ph);    // (1+eo)(ec+1)
                    v2f nh = ec - one;
                    const float rP = __builtin_amdgcn_rcpf(dh[0] * dh[1]);
                    v2f dsw = { dh[1], dh[0] };
                    v2f rPv = { rP, rP };
                    v2f hv  = (nh * dsw) * rPv;
                    h[u]     = hv[0];
                    h[u + 1] = hv[1];
                }
                unsigned q0 = pk16(h[0], h[1]);
                unsigned q1 = pk16(h[2], h[3]);
                unsigned q2 = pk16(h[4], h[5]);
                unsigned q3 = pk16(h[6], h[7]);
                auto s02 = __builtin_amdgcn_permlane32_swap(q0, q2, false, false);
                auto s13 = __builtin_amdgcn_permlane32_swap(q1, q3, false, false);
                u32x4 bw = { s02[0], s13[0], s02[1], s13[1] };
                bfrag[rb] = __builtin_bit_cast(f16x8, bw);
            }
        }

        // ---- final h straight from bfrag (lane holds units hi*8+e of its col) ----
        #pragma unroll
        for (int rb = 0; rb < 2; ++rb) {
            const int rr = wib * 64 + col + rb * 32;
            #pragma unroll
            for (int e = 0; e < 8; ++e)
                hbuf[rr][hi * 8 + e] = (float)bfrag[rb][e];
        }
        __syncthreads();

        // ---- fc stage: thread tid owns tile-local row tid ----
        const int grow = blockRow0 + tid;

        float x19[19];
        #pragma unroll
        for (int k = 0; k < 16; ++k) x19[k] = hbuf[tid][k];

        float ctl[5];
        #pragma unroll
        for (int k = 0; k < 5; ++k) ctl[k] = controls[(size_t)grow * 5 + k];
        #pragma unroll
        for (int j = 0; j < 3; ++j) {
            float a = b_cc[j];
            #pragma unroll
            for (int k = 0; k < 5; ++k) a = fmaf(ctl[k], W_cc[j * 5 + k], a);
            x19[16 + j] = a;
        }

        // fc1: Linear(19->16); tanh via pairwise-merged rcp
        float d1[16];
        #pragma unroll
        for (int j = 0; j < 16; ++j) {
            float a = b1[j];
            #pragma unroll
            for (int k = 0; k < 19; ++k) a = fmaf(x19[k], W1[j * 19 + k], a);
            d1[j] = fexp2((2.0f * LOG2E) * a) + 1.0f;
        }
        v2f t12[8];
        #pragma unroll
        for (int j = 0; j < 16; j += 2) {
            const float rP = __builtin_amdgcn_rcpf(d1[j] * d1[j + 1]);
            t12[j >> 1][0] = fmaf(-2.0f * d1[j + 1], rP, 1.0f);
            t12[j >> 1][1] = fmaf(-2.0f * d1[j],     rP, 1.0f);
        }

        // fc2: Linear(16->16) + tanh (packed fma, pairwise-merged rcp)
        float d2[16];
        #pragma unroll
        for (int j = 0; j < 16; ++j) {
            const v2f* w2row = (const v2f*)(W2 + j * 16);
            v2f a = t12[0] * w2row[0];
            #pragma unroll
            for (int p = 1; p < 8; ++p) a = __builtin_elementwise_fma(t12[p], w2row[p], a);
            d2[j] = fexp2((2.0f * LOG2E) * (a.x + a.y + b2[j])) + 1.0f;
        }
        v2f t22[8];
        #pragma unroll
        for (int j = 0; j < 16; j += 2) {
            const float rP = __builtin_amdgcn_rcpf(d2[j] * d2[j + 1]);
            t22[j >> 1][0] = fmaf(-2.0f * d2[j + 1], rP, 1.0f);
            t22[j >> 1][1] = fmaf(-2.0f * d2[j],     rP, 1.0f);
        }

        // fc3: Linear(16->1) + ReLU
        const v2f* w3p = (const v2f*)W3;
        v2f a3 = t22[0] * w3p[0];
        #pragma unroll
        for (int p = 1; p < 8; ++p) a3 = __builtin_elementwise_fma(t22[p], w3p[p], a3);
        const float r = a3.x + a3.y + b3[0];
        if (grow < Btot) out[grow] = fmaxf(r, 0.0f);

        __syncthreads();   // protect hbuf against next tile's writes
    }
}

extern "C" void kernel_launch(void* const* d_in, const int* in_sizes, int n_in,
                              void* d_out, int out_size, void* d_ws, size_t ws_size,
                              hipStream_t stream) {
    const float* mobility = (const float*)d_in[0];
    const float* controls = (const float*)d_in[1];
    // d_in[2] = last : unused by the reference
    const float* W_cc = (const float*)d_in[3];
    const float* b_cc = (const float*)d_in[4];
    const float* W_ih = (const float*)d_in[5];
    const float* W_hh = (const float*)d_in[6];
    const float* b_ih = (const float*)d_in[7];
    const float* b_hh = (const float*)d_in[8];
    const float* W1   = (const float*)d_in[9];
    const float* b1   = (const float*)d_in[10];
    const float* W2   = (const float*)d_in[11];
    const float* b2   = (const float*)d_in[12];
    const float* W3   = (const float*)d_in[13];
    const float* b3   = (const float*)d_in[14];
    float* out = (float*)d_out;

    const int Btot  = in_sizes[0] / 7;              // 1048576
    const int tiles = (Btot + 255) / 256;           // 4096
    const int grid  = tiles < 1024 ? tiles : 1024;  // 4 tiles/block, full residency

    lstm_mfma_kernel<<<grid, 256, 0, stream>>>(
        mobility, controls, W_cc, b_cc, W_ih, W_hh, b_ih, b_hh,
        W1, b1, W2, b2, W3, b3, out, Btot);
}